// Round 9
// baseline (2104.943 us; speedup 1.0000x reference)
//
#include <hip/hip_runtime.h>

#define D_MODEL 2048
#define NUM_TILES 64
#define D_SLICE 32
#define TILES_PER_CLUSTER 8
#define NUM_CLUSTERS 8
#define GRID_PTS 16
#define LN_EPS 1e-5f
#define NBUCKET 64

// native 4-float vector
typedef float f32x4 __attribute__((ext_vector_type(4)));

// order-preserving float<->uint map for atomic min/max
__device__ __forceinline__ unsigned int encF(float f) {
    unsigned int u = __float_as_uint(f);
    return (u & 0x80000000u) ? ~u : (u | 0x80000000u);
}
__device__ __forceinline__ float decF(unsigned int u) {
    unsigned int b = (u & 0x80000000u) ? (u ^ 0x80000000u) : ~u;
    return __uint_as_float(b);
}

// Kernel A: slope_sign per dim + init bucketed tile min/max + zero the
// done-counter (ws is poisoned once; re-init every call).
__global__ void kan_setup(const float* __restrict__ slopes,
                          float* __restrict__ sgn,
                          unsigned int* __restrict__ tminb,
                          unsigned int* __restrict__ tmaxb,
                          unsigned int* __restrict__ ctr) {
    int d = blockIdx.x * blockDim.x + threadIdx.x;  // 0..4095
    if (d == 0) *ctr = 0u;
    if (d < NUM_TILES * NBUCKET) { tminb[d] = 0xFFFFFFFFu; tmaxb[d] = 0u; }
    if (d < D_MODEL) {
        const float* p = slopes + (size_t)d * GRID_PTS;
        float s = 0.f;
#pragma unroll
        for (int k = 0; k < GRID_PTS; ++k) s += p[k];
        float m = s * (1.0f / GRID_PTS);
        sgn[d] = (m > 0.f) ? 1.f : ((m < 0.f) ? -1.f : 0.f);
    }
}

// Kernel B: one block per token. 2 barriers total. Fused one-pass mean/var,
// plain cached out=x copy, wave-redundant argmax (no serial section, no 3rd
// barrier), bucketed low-contention atomics, last-block bucket reduction.
__launch_bounds__(256)
__global__ void kan_main(const float* __restrict__ x,
                         const float* __restrict__ gamma,
                         const float* __restrict__ beta,
                         const float* __restrict__ sgn,
                         float* __restrict__ out,
                         float* __restrict__ xn_slice,
                         int* __restrict__ tidx_out,
                         unsigned int* __restrict__ tminb,
                         unsigned int* __restrict__ tmaxb,
                         unsigned int* __restrict__ ctr,
                         unsigned int* __restrict__ tmin,
                         unsigned int* __restrict__ tmax) {
    const int n = blockIdx.x;
    const int tid = threadIdx.x;
    const size_t base = (size_t)n * D_MODEL + (size_t)tid * 8;

    // load 8 contiguous dims (all within tile tid>>2)
    f32x4 a = *(const f32x4*)(x + base);
    f32x4 b = *(const f32x4*)(x + base + 4);

    // ---- out = x copy: plain cached stores, issued early ----
    *(f32x4*)(out + base) = a;
    *(f32x4*)(out + base + 4) = b;

    // ---- hoist weight loads (in flight during the reduction) ----
    f32x4 g0 = *(const f32x4*)(gamma + tid * 8);
    f32x4 g1 = *(const f32x4*)(gamma + tid * 8 + 4);
    f32x4 b0 = *(const f32x4*)(beta + tid * 8);
    f32x4 b1 = *(const f32x4*)(beta + tid * 8 + 4);
    f32x4 sg0 = *(const f32x4*)(sgn + tid * 8);
    f32x4 sg1 = *(const f32x4*)(sgn + tid * 8 + 4);

    float xv[8] = {a.x, a.y, a.z, a.w, b.x, b.y, b.z, b.w};

    __shared__ float2 red[4];
    __shared__ int ts[NUM_TILES];
    __shared__ int lastflag;

    // ---- fused sum + sumsq, single butterfly + barrier 1 ----
    float s = 0.f, q = 0.f;
#pragma unroll
    for (int k = 0; k < 8; ++k) { s += xv[k]; q += xv[k] * xv[k]; }
#pragma unroll
    for (int off = 32; off > 0; off >>= 1) {
        s += __shfl_xor(s, off);
        q += __shfl_xor(q, off);
    }
    if ((tid & 63) == 0) red[tid >> 6] = make_float2(s, q);
    __syncthreads();
    float S = red[0].x + red[1].x + red[2].x + red[3].x;
    float Q = red[0].y + red[1].y + red[2].y + red[3].y;
    const float mu = S * (1.0f / D_MODEL);
    float var = Q * (1.0f / D_MODEL) - mu * mu;
    var = fmaxf(var, 0.0f);
    const float rs = rsqrtf(var + LN_EPS);

    // ---- normalized values + integer sign score ----
    float gv[8] = {g0.x, g0.y, g0.z, g0.w, g1.x, g1.y, g1.z, g1.w};
    float bv[8] = {b0.x, b0.y, b0.z, b0.w, b1.x, b1.y, b1.z, b1.w};
    float sv[8] = {sg0.x, sg0.y, sg0.z, sg0.w, sg1.x, sg1.y, sg1.z, sg1.w};

    float xn[8];
    int sc = 0;
#pragma unroll
    for (int k = 0; k < 8; ++k) {
        xn[k] = (xv[k] - mu) * rs * gv[k] + bv[k];
        int s1 = (xn[k] > 0.f) ? 1 : ((xn[k] < 0.f) ? -1 : 0);
        sc += s1 * (int)sv[k];
    }
    sc += __shfl_xor(sc, 1);
    sc += __shfl_xor(sc, 2);
    if ((tid & 3) == 0) ts[tid >> 2] = sc;
    __syncthreads();  // barrier 2: ts complete

    // ---- wave-redundant argmax (no serial section, no extra barrier) ----
    // every thread: cluster sum for cluster (tid&7) via LDS broadcasts
    const int c8 = tid & 7;
    int cs = 0;
#pragma unroll
    for (int t = 0; t < TILES_PER_CLUSTER; ++t) cs += ts[c8 * TILES_PER_CLUSTER + t];
    // cluster key-max over the 8 lane-slots (ties -> smaller cluster)
    int key = ((cs + 512) << 3) | (7 - c8);
    key = max(key, __shfl_xor(key, 1));
    key = max(key, __shfl_xor(key, 2));
    key = max(key, __shfl_xor(key, 4));
    const int bc = 7 - (key & 7);  // winning cluster, wave-uniform
    // tile key-max within cluster bc (ties -> smaller tile)
    int sct = ts[bc * TILES_PER_CLUSTER + c8];
    int key2 = ((sct + 64) << 3) | (7 - c8);
    key2 = max(key2, __shfl_xor(key2, 1));
    key2 = max(key2, __shfl_xor(key2, 2));
    key2 = max(key2, __shfl_xor(key2, 4));
    const int kwin = 7 - (key2 & 7);
    const int tile = bc * TILES_PER_CLUSTER + kwin;  // uniform

    if (tid == 0) tidx_out[n] = tile;

    // ---- stash xn slice of chosen tile (4 threads, 128B contiguous) ----
    if ((tid >> 2) == tile) {
        float* qp = xn_slice + (size_t)n * D_SLICE + (tid & 3) * 8;
        *(f32x4*)(qp) = f32x4{xn[0], xn[1], xn[2], xn[3]};
        *(f32x4*)(qp + 4) = f32x4{xn[4], xn[5], xn[6], xn[7]};
    }

    // ---- chosen-tile min/max -> bucketed atomics (contention / 64) ----
    float mn8 = xn[0], mx8 = xn[0];
#pragma unroll
    for (int k = 1; k < 8; ++k) { mn8 = fminf(mn8, xn[k]); mx8 = fmaxf(mx8, xn[k]); }
    mn8 = fminf(mn8, __shfl_xor(mn8, 1));
    mn8 = fminf(mn8, __shfl_xor(mn8, 2));
    mx8 = fmaxf(mx8, __shfl_xor(mx8, 1));
    mx8 = fmaxf(mx8, __shfl_xor(mx8, 2));
    if (tid == tile * 4) {
        int bkt = blockIdx.x & (NBUCKET - 1);
        atomicMin(&tminb[tile * NBUCKET + bkt], encF(mn8));
        atomicMax(&tmaxb[tile * NBUCKET + bkt], encF(mx8));
    }

    // ---- last-block tail: reduce 64 buckets -> tmin/tmax (kills a launch) --
    __threadfence();
    __syncthreads();
    if (tid == 0) {
        unsigned int o = atomicAdd(ctr, 1u);
        lastflag = (o == gridDim.x - 1) ? 1 : 0;
    }
    __syncthreads();
    if (lastflag && tid < NUM_TILES) {
        unsigned int mn = 0xFFFFFFFFu, mx = 0u;
#pragma unroll 8
        for (int bkt = 0; bkt < NBUCKET; ++bkt) {
            mn = min(mn, __hip_atomic_load(tminb + tid * NBUCKET + bkt,
                                           __ATOMIC_RELAXED, __HIP_MEMORY_SCOPE_AGENT));
            mx = max(mx, __hip_atomic_load(tmaxb + tid * NBUCKET + bkt,
                                           __ATOMIC_RELAXED, __HIP_MEMORY_SCOPE_AGENT));
        }
        tmin[tid] = mn;
        tmax[tid] = mx;
    }
}

// Kernel C: one thread per (token, quad). Spline delta, float4 RMW on out.
__global__ void kan_apply(const float* __restrict__ xn_slice,
                          const int* __restrict__ tidx,
                          const float* __restrict__ bases,
                          const float* __restrict__ slopes,
                          const float* __restrict__ oscale,
                          const unsigned int* __restrict__ tmin,
                          const unsigned int* __restrict__ tmax,
                          float* __restrict__ out, int N) {
    int g = blockIdx.x * blockDim.x + threadIdx.x;
    if (g >= N * 8) return;
    int n = g >> 3;
    int qd = g & 7;  // quad of 4 dims: j = 4*qd..4*qd+3
    int t = tidx[n];
    f32x4 xn4 = *(const f32x4*)(xn_slice + (size_t)n * D_SLICE + qd * 4);
    float mn = decF(tmin[t]);
    float mx = decF(tmax[t]);
    float inv = 1.0f / (mx - mn + 1e-8f);
    float osc = oscale[t];

    float dl[4];
    float xnv[4] = {xn4.x, xn4.y, xn4.z, xn4.w};
#pragma unroll
    for (int e = 0; e < 4; ++e) {
        float u = (xnv[e] - mn) * inv;
        u = fminf(fmaxf(u, 0.0f), 1.0f - 1e-6f);
        int gi = (int)(u * (float)GRID_PTS);
        gi = min(max(gi, 0), GRID_PTS - 1);
        int j = qd * 4 + e;
        int off = (t * D_SLICE + j) * GRID_PTS + gi;
        float xl = (u - (float)gi * (1.0f / GRID_PTS)) * (float)GRID_PTS;
        dl[e] = (bases[off] + slopes[off] * xl) * osc;
    }
    size_t oi = (size_t)n * D_MODEL + t * D_SLICE + qd * 4;
    f32x4 o = *(f32x4*)(out + oi);
    o.x += dl[0]; o.y += dl[1]; o.z += dl[2]; o.w += dl[3];
    *(f32x4*)(out + oi) = o;
}

extern "C" void kernel_launch(void* const* d_in, const int* in_sizes, int n_in,
                              void* d_out, int out_size, void* d_ws, size_t ws_size,
                              hipStream_t stream) {
    const float* x      = (const float*)d_in[0];
    const float* gamma  = (const float*)d_in[1];
    const float* beta   = (const float*)d_in[2];
    const float* bases  = (const float*)d_in[3];
    const float* slopes = (const float*)d_in[4];
    const float* oscale = (const float*)d_in[5];
    float* out = (float*)d_out;
    const int N = in_sizes[0] / D_MODEL;  // 16384

    // workspace layout
    char* w = (char*)d_ws;
    unsigned int* tminb = (unsigned int*)w; w += NUM_TILES * NBUCKET * 4;
    unsigned int* tmaxb = (unsigned int*)w; w += NUM_TILES * NBUCKET * 4;
    unsigned int* tmin  = (unsigned int*)w; w += 256;
    unsigned int* tmax  = (unsigned int*)w; w += 256;
    unsigned int* ctr   = (unsigned int*)w; w += 256;
    float* sgn = (float*)w;  w += D_MODEL * sizeof(float);
    int* tidx = (int*)w;     w += (size_t)N * sizeof(int);
    float* xns = (float*)w;  w += (size_t)N * D_SLICE * sizeof(float);

    kan_setup<<<(NUM_TILES * NBUCKET + 255) / 256, 256, 0, stream>>>(slopes, sgn,
                                                                     tminb, tmaxb, ctr);
    kan_main<<<N, 256, 0, stream>>>(x, gamma, beta, sgn, out, xns, tidx,
                                    tminb, tmaxb, ctr, tmin, tmax);
    kan_apply<<<(N * 8 + 255) / 256, 256, 0, stream>>>(xns, tidx, bases, slopes,
                                                       oscale, tmin, tmax, out, N);
}

// Round 10
// 70.807 us; speedup vs baseline: 29.7280x; 29.7280x over previous
//
#include <hip/hip_runtime.h>

#define D_MODEL 2048
#define NUM_TILES 64
#define D_SLICE 32
#define TILES_PER_CLUSTER 8
#define NUM_CLUSTERS 8
#define GRID_PTS 16
#define LN_EPS 1e-5f
#define NBUCKET 64

// native 4-float vector
typedef float f32x4 __attribute__((ext_vector_type(4)));

// order-preserving float<->uint map for atomic min/max
__device__ __forceinline__ unsigned int encF(float f) {
    unsigned int u = __float_as_uint(f);
    return (u & 0x80000000u) ? ~u : (u | 0x80000000u);
}
__device__ __forceinline__ float decF(unsigned int u) {
    unsigned int b = (u & 0x80000000u) ? (u ^ 0x80000000u) : ~u;
    return __uint_as_float(b);
}

// Kernel A: slope_sign per dim + init bucketed tile min/max (ws is poisoned).
__global__ void kan_setup(const float* __restrict__ slopes,
                          float* __restrict__ sgn,
                          unsigned int* __restrict__ tminb,
                          unsigned int* __restrict__ tmaxb) {
    int d = blockIdx.x * blockDim.x + threadIdx.x;  // 0..4095
    if (d < NUM_TILES * NBUCKET) { tminb[d] = 0xFFFFFFFFu; tmaxb[d] = 0u; }
    if (d < D_MODEL) {
        const float* p = slopes + (size_t)d * GRID_PTS;
        float s = 0.f;
#pragma unroll
        for (int k = 0; k < GRID_PTS; ++k) s += p[k];
        float m = s * (1.0f / GRID_PTS);
        sgn[d] = (m > 0.f) ? 1.f : ((m < 0.f) ? -1.f : 0.f);
    }
}

// Kernel B: one block per token. 2 barriers, no serial section, no fences.
// Fused one-pass mean/var, plain cached out=x copy, wave-redundant argmax,
// bucketed low-contention atomics.
__launch_bounds__(256)
__global__ void kan_main(const float* __restrict__ x,
                         const float* __restrict__ gamma,
                         const float* __restrict__ beta,
                         const float* __restrict__ sgn,
                         float* __restrict__ out,
                         float* __restrict__ xn_slice,
                         int* __restrict__ tidx_out,
                         unsigned int* __restrict__ tminb,
                         unsigned int* __restrict__ tmaxb) {
    const int n = blockIdx.x;
    const int tid = threadIdx.x;
    const size_t base = (size_t)n * D_MODEL + (size_t)tid * 8;

    // load 8 contiguous dims (all within tile tid>>2)
    f32x4 a = *(const f32x4*)(x + base);
    f32x4 b = *(const f32x4*)(x + base + 4);

    // ---- out = x copy: plain cached stores, issued early ----
    *(f32x4*)(out + base) = a;
    *(f32x4*)(out + base + 4) = b;

    // ---- hoist weight loads (in flight during the reduction) ----
    f32x4 g0 = *(const f32x4*)(gamma + tid * 8);
    f32x4 g1 = *(const f32x4*)(gamma + tid * 8 + 4);
    f32x4 b0 = *(const f32x4*)(beta + tid * 8);
    f32x4 b1 = *(const f32x4*)(beta + tid * 8 + 4);
    f32x4 sg0 = *(const f32x4*)(sgn + tid * 8);
    f32x4 sg1 = *(const f32x4*)(sgn + tid * 8 + 4);

    float xv[8] = {a.x, a.y, a.z, a.w, b.x, b.y, b.z, b.w};

    __shared__ float2 red[4];
    __shared__ int ts[NUM_TILES];

    // ---- fused sum + sumsq, single butterfly + barrier 1 ----
    float s = 0.f, q = 0.f;
#pragma unroll
    for (int k = 0; k < 8; ++k) { s += xv[k]; q += xv[k] * xv[k]; }
#pragma unroll
    for (int off = 32; off > 0; off >>= 1) {
        s += __shfl_xor(s, off);
        q += __shfl_xor(q, off);
    }
    if ((tid & 63) == 0) red[tid >> 6] = make_float2(s, q);
    __syncthreads();
    float S = red[0].x + red[1].x + red[2].x + red[3].x;
    float Q = red[0].y + red[1].y + red[2].y + red[3].y;
    const float mu = S * (1.0f / D_MODEL);
    float var = Q * (1.0f / D_MODEL) - mu * mu;
    var = fmaxf(var, 0.0f);
    const float rs = rsqrtf(var + LN_EPS);

    // ---- normalized values + integer sign score ----
    float gv[8] = {g0.x, g0.y, g0.z, g0.w, g1.x, g1.y, g1.z, g1.w};
    float bv[8] = {b0.x, b0.y, b0.z, b0.w, b1.x, b1.y, b1.z, b1.w};
    float sv[8] = {sg0.x, sg0.y, sg0.z, sg0.w, sg1.x, sg1.y, sg1.z, sg1.w};

    float xn[8];
    int sc = 0;
#pragma unroll
    for (int k = 0; k < 8; ++k) {
        xn[k] = (xv[k] - mu) * rs * gv[k] + bv[k];
        int s1 = (xn[k] > 0.f) ? 1 : ((xn[k] < 0.f) ? -1 : 0);
        sc += s1 * (int)sv[k];
    }
    sc += __shfl_xor(sc, 1);
    sc += __shfl_xor(sc, 2);
    if ((tid & 3) == 0) ts[tid >> 2] = sc;
    __syncthreads();  // barrier 2: ts complete

    // ---- wave-redundant argmax (no serial section, no extra barrier) ----
    // every thread: cluster sum for cluster (tid&7) via LDS broadcasts
    const int c8 = tid & 7;
    int cs = 0;
#pragma unroll
    for (int t = 0; t < TILES_PER_CLUSTER; ++t) cs += ts[c8 * TILES_PER_CLUSTER + t];
    // cluster key-max over the 8 lane-slots (ties -> smaller cluster)
    int key = ((cs + 512) << 3) | (7 - c8);
    key = max(key, __shfl_xor(key, 1));
    key = max(key, __shfl_xor(key, 2));
    key = max(key, __shfl_xor(key, 4));
    const int bc = 7 - (key & 7);  // winning cluster, wave-uniform
    // tile key-max within cluster bc (ties -> smaller tile)
    int sct = ts[bc * TILES_PER_CLUSTER + c8];
    int key2 = ((sct + 64) << 3) | (7 - c8);
    key2 = max(key2, __shfl_xor(key2, 1));
    key2 = max(key2, __shfl_xor(key2, 2));
    key2 = max(key2, __shfl_xor(key2, 4));
    const int kwin = 7 - (key2 & 7);
    const int tile = bc * TILES_PER_CLUSTER + kwin;  // uniform

    if (tid == 0) tidx_out[n] = tile;

    // ---- stash xn slice of chosen tile (4 threads, 128B contiguous) ----
    if ((tid >> 2) == tile) {
        float* qp = xn_slice + (size_t)n * D_SLICE + (tid & 3) * 8;
        *(f32x4*)(qp) = f32x4{xn[0], xn[1], xn[2], xn[3]};
        *(f32x4*)(qp + 4) = f32x4{xn[4], xn[5], xn[6], xn[7]};
    }

    // ---- chosen-tile min/max -> bucketed atomics (contention / 64) ----
    float mn8 = xn[0], mx8 = xn[0];
#pragma unroll
    for (int k = 1; k < 8; ++k) { mn8 = fminf(mn8, xn[k]); mx8 = fmaxf(mx8, xn[k]); }
    mn8 = fminf(mn8, __shfl_xor(mn8, 1));
    mn8 = fminf(mn8, __shfl_xor(mn8, 2));
    mx8 = fmaxf(mx8, __shfl_xor(mx8, 1));
    mx8 = fmaxf(mx8, __shfl_xor(mx8, 2));
    if (tid == tile * 4) {
        int bkt = blockIdx.x & (NBUCKET - 1);
        atomicMin(&tminb[tile * NBUCKET + bkt], encF(mn8));
        atomicMax(&tmaxb[tile * NBUCKET + bkt], encF(mx8));
    }
}

// Kernel B2: reduce 64 buckets -> final per-tile min/max. One block, 64 thr.
__global__ void kan_reduce(const unsigned int* __restrict__ tminb,
                           const unsigned int* __restrict__ tmaxb,
                           unsigned int* __restrict__ tmin,
                           unsigned int* __restrict__ tmax) {
    int t = threadIdx.x;  // 0..63
    unsigned int mn = 0xFFFFFFFFu, mx = 0u;
#pragma unroll 4
    for (int b = 0; b < NBUCKET; ++b) {
        mn = min(mn, tminb[t * NBUCKET + b]);
        mx = max(mx, tmaxb[t * NBUCKET + b]);
    }
    tmin[t] = mn;
    tmax[t] = mx;
}

// Kernel C: one thread per (token, quad). Spline delta, float4 RMW on out.
__global__ void kan_apply(const float* __restrict__ xn_slice,
                          const int* __restrict__ tidx,
                          const float* __restrict__ bases,
                          const float* __restrict__ slopes,
                          const float* __restrict__ oscale,
                          const unsigned int* __restrict__ tmin,
                          const unsigned int* __restrict__ tmax,
                          float* __restrict__ out, int N) {
    int g = blockIdx.x * blockDim.x + threadIdx.x;
    if (g >= N * 8) return;
    int n = g >> 3;
    int qd = g & 7;  // quad of 4 dims: j = 4*qd..4*qd+3
    int t = tidx[n];
    f32x4 xn4 = *(const f32x4*)(xn_slice + (size_t)n * D_SLICE + qd * 4);
    float mn = decF(tmin[t]);
    float mx = decF(tmax[t]);
    float inv = 1.0f / (mx - mn + 1e-8f);
    float osc = oscale[t];

    float dl[4];
    float xnv[4] = {xn4.x, xn4.y, xn4.z, xn4.w};
#pragma unroll
    for (int e = 0; e < 4; ++e) {
        float u = (xnv[e] - mn) * inv;
        u = fminf(fmaxf(u, 0.0f), 1.0f - 1e-6f);
        int gi = (int)(u * (float)GRID_PTS);
        gi = min(max(gi, 0), GRID_PTS - 1);
        int j = qd * 4 + e;
        int off = (t * D_SLICE + j) * GRID_PTS + gi;
        float xl = (u - (float)gi * (1.0f / GRID_PTS)) * (float)GRID_PTS;
        dl[e] = (bases[off] + slopes[off] * xl) * osc;
    }
    size_t oi = (size_t)n * D_MODEL + t * D_SLICE + qd * 4;
    f32x4 o = *(f32x4*)(out + oi);
    o.x += dl[0]; o.y += dl[1]; o.z += dl[2]; o.w += dl[3];
    *(f32x4*)(out + oi) = o;
}

extern "C" void kernel_launch(void* const* d_in, const int* in_sizes, int n_in,
                              void* d_out, int out_size, void* d_ws, size_t ws_size,
                              hipStream_t stream) {
    const float* x      = (const float*)d_in[0];
    const float* gamma  = (const float*)d_in[1];
    const float* beta   = (const float*)d_in[2];
    const float* bases  = (const float*)d_in[3];
    const float* slopes = (const float*)d_in[4];
    const float* oscale = (const float*)d_in[5];
    float* out = (float*)d_out;
    const int N = in_sizes[0] / D_MODEL;  // 16384

    // workspace layout
    char* w = (char*)d_ws;
    unsigned int* tminb = (unsigned int*)w; w += NUM_TILES * NBUCKET * 4;
    unsigned int* tmaxb = (unsigned int*)w; w += NUM_TILES * NBUCKET * 4;
    unsigned int* tmin  = (unsigned int*)w; w += 256;
    unsigned int* tmax  = (unsigned int*)w; w += 256;
    float* sgn = (float*)w;  w += D_MODEL * sizeof(float);
    int* tidx = (int*)w;     w += (size_t)N * sizeof(int);
    float* xns = (float*)w;  w += (size_t)N * D_SLICE * sizeof(float);

    kan_setup<<<(NUM_TILES * NBUCKET + 255) / 256, 256, 0, stream>>>(slopes, sgn, tminb, tmaxb);
    kan_main<<<N, 256, 0, stream>>>(x, gamma, beta, sgn, out, xns, tidx, tminb, tmaxb);
    kan_reduce<<<1, 64, 0, stream>>>(tminb, tmaxb, tmin, tmax);
    kan_apply<<<(N * 8 + 255) / 256, 256, 0, stream>>>(xns, tidx, bases, slopes,
                                                       oscale, tmin, tmax, out, N);
}